// Round 4
// baseline (162.901 us; speedup 1.0000x reference)
//
#include <hip/hip_runtime.h>
#include <hip/hip_bf16.h>

#define B_ 4
#define N_ 4096
#define L_ 4104
#define D_ 512
#define RT 17
#define JC2 32
#define CH2 129

typedef __attribute__((ext_vector_type(8))) short bf16x8;
typedef __attribute__((ext_vector_type(4))) float f32x4;

#define AS1(p) ((__attribute__((address_space(1))) const void*)(p))
#define AS3(p) ((__attribute__((address_space(3))) void*)(p))

__device__ __forceinline__ float bf2f(unsigned short u) {
  union { unsigned u; float f; } c; c.u = ((unsigned)u) << 16; return c.f;
}

// ---------------- K0: fused [proj_w f32->bf16] + [emb gather + depthwise conv -> y bf16] ----------------
__global__ __launch_bounds__(256) void k_pre(const float* __restrict__ pw,
    __hip_bfloat16* __restrict__ Wbf,
    const int* __restrict__ x, const float* __restrict__ emb,
    const float* __restrict__ conv_w, const float* __restrict__ conv_b,
    unsigned* __restrict__ y) {
  const int bx = blockIdx.x;
  const int t = threadIdx.x;
  if (bx < 1024) {                       // cvt: 1024*256 == 512*512
    const int i = bx * 256 + t;
    Wbf[i] = __float2bfloat16(pw[i]);
    return;
  }
  const int row = bx - 1024;             // b*N_ + i
  const int b = row >> 12, i = row & (N_ - 1);
  const int d = t * 2;
  const float4 c0 = ((const float4*)conv_w)[d];
  const float4 c1 = ((const float4*)conv_w)[d + 1];
  const float ca[4] = {c0.x, c0.y, c0.z, c0.w};
  const float cb[4] = {c1.x, c1.y, c1.z, c1.w};
  float2 acc = ((const float2*)conv_b)[t];
#pragma unroll
  for (int k = 0; k < 4; ++k) {
    if (i + k < N_) {
      const int tok = x[b * N_ + i + k];
      const float2 e = *(const float2*)(emb + (size_t)tok * D_ + d);
      acc.x += e.x * ca[k];
      acc.y += e.y * cb[k];
    }
  }
  union { __hip_bfloat16 h[2]; unsigned u; } pk;
  pk.h[0] = __float2bfloat16(acc.x);
  pk.h[1] = __float2bfloat16(acc.y);
  y[(size_t)row * 256 + t] = pk.u;
}

// ---------------- K1: h = y @ proj_w^T + proj_b (bf16 out) + t-partials ----------------
__global__ __launch_bounds__(256) void k_gemm(const __hip_bfloat16* __restrict__ A,
    const __hip_bfloat16* __restrict__ W, const float* __restrict__ bias,
    const float* __restrict__ sw,
    __hip_bfloat16* __restrict__ C, float* __restrict__ tbP) {
  __shared__ __align__(16) __hip_bfloat16 As[128 * 32];
  __shared__ __align__(16) __hip_bfloat16 Bs[128 * 32];
  const int t = threadIdx.x;
  const int m0 = blockIdx.x * 128, n0 = blockIdx.y * 128;
  const int w = t >> 6, l = t & 63;
  const int quad = l >> 4, r16 = l & 15;
  const int wr = (w >> 1) * 64, wc = (w & 1) * 64;

  f32x4 acc[4][4];
#pragma unroll
  for (int a = 0; a < 4; ++a)
#pragma unroll
    for (int bq = 0; bq < 4; ++bq) acc[a][bq] = (f32x4){0.f, 0.f, 0.f, 0.f};

  const int srow = t >> 2;
  const int scol = (t & 3) * 8;
  const int ldsb = (t & 192) * 16;

#pragma unroll 1
  for (int kt = 0; kt < 16; ++kt) {
    const int kb = kt * 32;
    __builtin_amdgcn_global_load_lds(AS1(A + ((size_t)(m0 + srow)) * 512 + kb + scol),
                                     AS3((char*)As + ldsb), 16, 0, 0);
    __builtin_amdgcn_global_load_lds(AS1(A + ((size_t)(m0 + 64 + srow)) * 512 + kb + scol),
                                     AS3((char*)As + 4096 + ldsb), 16, 0, 0);
    __builtin_amdgcn_global_load_lds(AS1(W + ((size_t)(n0 + srow)) * 512 + kb + scol),
                                     AS3((char*)Bs + ldsb), 16, 0, 0);
    __builtin_amdgcn_global_load_lds(AS1(W + ((size_t)(n0 + 64 + srow)) * 512 + kb + scol),
                                     AS3((char*)Bs + 4096 + ldsb), 16, 0, 0);
    __syncthreads();

    bf16x8 af[4], bf[4];
#pragma unroll
    for (int ti = 0; ti < 4; ++ti)
      af[ti] = *(const bf16x8*)(As + (wr + ti * 16 + r16) * 32 + quad * 8);
#pragma unroll
    for (int tj = 0; tj < 4; ++tj)
      bf[tj] = *(const bf16x8*)(Bs + (wc + tj * 16 + r16) * 32 + quad * 8);
#pragma unroll
    for (int ti = 0; ti < 4; ++ti)
#pragma unroll
      for (int tj = 0; tj < 4; ++tj)
        acc[ti][tj] = __builtin_amdgcn_mfma_f32_16x16x32_bf16(af[ti], bf[tj], acc[ti][tj], 0, 0, 0);
    __syncthreads();
  }

  float swv[4];
#pragma unroll
  for (int tj = 0; tj < 4; ++tj) swv[tj] = sw[n0 + wc + tj * 16 + r16];

  float tpart[4][4];
#pragma unroll
  for (int ti = 0; ti < 4; ++ti) {
    const int gi0 = m0 + wr + ti * 16 + quad * 4;
#pragma unroll
    for (int r = 0; r < 4; ++r) tpart[ti][r] = 0.f;
#pragma unroll
    for (int tj = 0; tj < 4; ++tj) {
      const int go = n0 + wc + tj * 16 + r16;
      const float bv = bias[go];
#pragma unroll
      for (int r = 0; r < 4; ++r) {
        const float cf = acc[ti][tj][r] + bv;
        C[(size_t)(gi0 + r) * 512 + go] = __float2bfloat16(cf);
        tpart[ti][r] = fmaf(cf, swv[tj], tpart[ti][r]);
      }
    }
  }
#pragma unroll
  for (int ti = 0; ti < 4; ++ti)
#pragma unroll
    for (int r = 0; r < 4; ++r) {
      float v = tpart[ti][r];
      v += __shfl_xor(v, 1); v += __shfl_xor(v, 2);
      v += __shfl_xor(v, 4); v += __shfl_xor(v, 8);
      tpart[ti][r] = v;
    }
  if (r16 == 0) {
    const int p = blockIdx.y * 2 + (w & 1);
#pragma unroll
    for (int ti = 0; ti < 4; ++ti)
#pragma unroll
      for (int r = 0; r < 4; ++r)
        tbP[(size_t)p * 16384 + (m0 + wr + ti * 16 + quad * 4 + r)] = tpart[ti][r];
  }
}

// helper: 4-way softmax from a t-window in LDS
__device__ __forceinline__ float4 softmax4(const float* __restrict__ tw, int base,
                                           int i, float bb) {
  const float s0 = tw[i - base] + bb;
  const int j2 = i & ~1;
  const float s1 = (tw[j2 - base] + tw[j2 + 1 - base]) * 0.5f + bb;
  const int j3 = (i / 3) * 3;
  const float s2 = (tw[j3 - base] + tw[j3 + 1 - base] + tw[j3 + 2 - base]) * (1.f / 3.f) + bb;
  const int j4 = i & ~3;
  const float s3 = (tw[j4 - base] + tw[j4 + 1 - base] + tw[j4 + 2 - base] + tw[j4 + 3 - base]) * 0.25f + bb;
  const float m = fmaxf(fmaxf(s0, s1), fmaxf(s2, s3));
  const float e0 = __expf(s0 - m), e1 = __expf(s1 - m), e2 = __expf(s2 - m), e3 = __expf(s3 - m);
  const float inv = 1.f / (e0 + e1 + e2 + e3);
  return make_float4(e0 * inv, e1 * inv, e2 * inv, e3 * inv);
}

// ---------------- K2: consensus attention; recomputes S rows from tbP in-block ----------------
__global__ __launch_bounds__(256) void k_attn(const float* __restrict__ tbP,
    const float* __restrict__ sb,
    float4* __restrict__ accnP, float* __restrict__ accdP) {
  __shared__ float twi[262];
  __shared__ float twj[135];
  __shared__ __align__(16) float4 Sch[CH2];
  const int bx = blockIdx.x;
  const int jc = bx & (JC2 - 1);
  const int rt = (bx >> 5) % RT;
  const int b  = bx / (JC2 * RT);
  const int t = threadIdx.x;
  const int j0 = jc * CH2;
  const int i0 = rt * 256;
  const int rowb = b * N_;
  // t-window for this block's i-range: [i0-3, i0+258]
  for (int idx = t; idx < 262; idx += 256) {
    const int j = i0 - 3 + idx;
    float v = 0.f;
    if (j >= 0 && j < N_) {
#pragma unroll
      for (int p = 0; p < 8; ++p) v += tbP[(size_t)p * 16384 + rowb + j];
    }
    twi[idx] = v;
  }
  // t-window for the j-chunk: [j0-3, j0+131]
  for (int idx = t; idx < 135; idx += 256) {
    const int j = j0 - 3 + idx;
    float v = 0.f;
    if (j >= 0 && j < N_) {
#pragma unroll
      for (int p = 0; p < 8; ++p) v += tbP[(size_t)p * 16384 + rowb + j];
    }
    twj[idx] = v;
  }
  __syncthreads();
  const float bb = sb[0];
  if (t < CH2 && j0 + t < L_) Sch[t] = softmax4(twj, j0 - 3, j0 + t, bb);
  const int i = i0 + t;
  const float4 si = softmax4(twi, i0 - 3, i, bb);   // safe for i>=L_ (unused)
  __syncthreads();
  if (i < L_) {
    const int len = min(CH2, L_ - j0);
    float l = 0.f, a0 = 0.f, a1 = 0.f, a2 = 0.f, a3 = 0.f;
#pragma unroll 4
    for (int jj = 0; jj < len; ++jj) {
      const float4 v = Sch[jj];
      const float dot = fmaf(si.x, v.x, fmaf(si.y, v.y, fmaf(si.z, v.z, si.w * v.w)));
      const float e = __expf(dot);   // dot in (0,1]; no max-shift needed
      l += e;
      a0 = fmaf(e, v.x, a0); a1 = fmaf(e, v.y, a1);
      a2 = fmaf(e, v.z, a2); a3 = fmaf(e, v.w, a3);
    }
    const size_t base = (size_t)jc * (B_ * L_) + b * L_ + i;
    accnP[base] = make_float4(a0, a1, a2, a3);
    accdP[base] = l;
  }
}

// ---------------- K3: 12-row tiles: reduce attn partials -> wgt, pool h once, downsample ----------------
__global__ __launch_bounds__(256) void k_fuse(const __hip_bfloat16* __restrict__ h,
    const float4* __restrict__ accnP, const float* __restrict__ accdP,
    float* __restrict__ out) {
  __shared__ __align__(16) float4 wgtS[12];
  const int bx = blockIdx.x;
  const int b = bx / 342, j12 = bx % 342;
  const int t = threadIdx.x, d = t * 2;
  const int r0 = 12 * j12;

  // phase 1: threads 0..191 reduce 32 j-chunk partials for rows r0..r0+11
  if (t < 192) {
    const int r = t >> 4, q = t & 15;
    const size_t i1 = (size_t)q * (B_ * L_) + b * L_ + r0 + r;
    const size_t i2 = (size_t)(q + 16) * (B_ * L_) + b * L_ + r0 + r;
    float4 nv = accnP[i1];
    const float4 n2 = accnP[i2];
    nv.x += n2.x; nv.y += n2.y; nv.z += n2.z; nv.w += n2.w;
    float dv = accdP[i1] + accdP[i2];
#pragma unroll
    for (int m = 8; m >= 1; m >>= 1) {   // xor within 16-lane row-groups
      nv.x += __shfl_xor(nv.x, m); nv.y += __shfl_xor(nv.y, m);
      nv.z += __shfl_xor(nv.z, m); nv.w += __shfl_xor(nv.w, m);
      dv   += __shfl_xor(dv, m);
    }
    if (q == 0) {
      const float inv = 1.f / dv;
      wgtS[r] = make_float4(nv.x * inv, nv.y * inv, nv.z * inv, nv.w * inv);
    }
  }
  __syncthreads();

  const __hip_bfloat16* hb = h + (size_t)b * N_ * D_;
  float2 hv[12];
#pragma unroll
  for (int q = 0; q < 12; ++q) {
    const int row = r0 + q;
    if (row < N_) {
      const ushort2 u = *(const ushort2*)(hb + (size_t)row * D_ + d);
      hv[q] = make_float2(bf2f(u.x), bf2f(u.y));
    } else {
      hv[q] = make_float2(0.f, 0.f);
    }
  }

  float2 p2[6], p3[4], p4[3];
#pragma unroll
  for (int g = 0; g < 6; ++g) {
    p2[g].x = (hv[2 * g].x + hv[2 * g + 1].x) * 0.5f;
    p2[g].y = (hv[2 * g].y + hv[2 * g + 1].y) * 0.5f;
  }
#pragma unroll
  for (int g = 0; g < 4; ++g) {
    p3[g].x = (hv[3 * g].x + hv[3 * g + 1].x + hv[3 * g + 2].x) * (1.f / 3.f);
    p3[g].y = (hv[3 * g].y + hv[3 * g + 1].y + hv[3 * g + 2].y) * (1.f / 3.f);
  }
#pragma unroll
  for (int g = 0; g < 3; ++g) {
    p4[g].x = (hv[4 * g].x + hv[4 * g + 1].x + hv[4 * g + 2].x + hv[4 * g + 3].x) * 0.25f;
    p4[g].y = (hv[4 * g].y + hv[4 * g + 1].y + hv[4 * g + 2].y + hv[4 * g + 3].y) * 0.25f;
  }

#pragma unroll
  for (int o = 0; o < 3; ++o) {
    const int orow = j12 * 3 + o;
    if (orow < 1024) {
      float ox = 0.f, oy = 0.f;
#pragma unroll
      for (int rr = 0; rr < 4; ++rr) {
        const int r = 4 * o + rr;
        const float4 w = wgtS[r];
        const float2 p1 = hv[r];
        const float2 q2 = p2[r >> 1];
        const float2 q3 = p3[r / 3];
        const float2 q4 = p4[o];
        ox += w.x * p1.x + w.y * q2.x + w.z * q3.x + w.w * q4.x;
        oy += w.x * p1.y + w.y * q2.y + w.z * q3.y + w.w * q4.y;
      }
      float2 ov; ov.x = ox * 0.25f; ov.y = oy * 0.25f;
      *(float2*)(out + (size_t)(b * 1024 + orow) * D_ + d) = ov;
    }
  }
}

extern "C" void kernel_launch(void* const* d_in, const int* in_sizes, int n_in,
                              void* d_out, int out_size, void* d_ws, size_t ws_size,
                              hipStream_t stream) {
  const int*   x       = (const int*)d_in[0];
  const float* emb     = (const float*)d_in[1];
  const float* conv_w  = (const float*)d_in[2];
  const float* conv_b  = (const float*)d_in[3];
  const float* proj_w  = (const float*)d_in[4];
  const float* proj_b  = (const float*)d_in[5];
  const float* score_w = (const float*)d_in[6];
  const float* score_b = (const float*)d_in[7];
  float* out = (float*)d_out;

  char* ws = (char*)d_ws;
  size_t off = 0;
  __hip_bfloat16* Wbf = (__hip_bfloat16*)(ws + off); off += (size_t)512 * 512 * 2;
  char*           ybase = ws + off;                  off += (size_t)16384 * 512 * 2;
  __hip_bfloat16* h   = (__hip_bfloat16*)(ws + off); off += (size_t)16384 * 512 * 2;
  float*          tbP = (float*)(ws + off);          off += (size_t)8 * 16384 * 4;
  // partials alias the y buffer (y dead after k_gemm): 8.4 MB + 2.1 MB <= 16 MB
  unsigned* y     = (unsigned*)ybase;
  float4*   accnP = (float4*)ybase;
  float*    accdP = (float*)(ybase + (size_t)JC2 * B_ * L_ * 16);
  (void)in_sizes; (void)n_in; (void)out_size; (void)ws_size;

  k_pre<<<1024 + B_ * N_, 256, 0, stream>>>(proj_w, Wbf, x, emb, conv_w, conv_b, y);
  k_gemm<<<dim3(128, 4), 256, 0, stream>>>((const __hip_bfloat16*)y, Wbf, proj_b, score_w,
                                           h, tbP);
  k_attn<<<B_ * RT * JC2, 256, 0, stream>>>(tbP, score_b, accnP, accdP);
  k_fuse<<<B_ * 342, 256, 0, stream>>>(h, accnP, accdP, out);
}

// Round 5
// 130.054 us; speedup vs baseline: 1.2526x; 1.2526x over previous
//
#include <hip/hip_runtime.h>
#include <hip/hip_bf16.h>

#define B_ 4
#define N_ 4096
#define L_ 4104
#define D_ 512
#define RT 17
#define JC2 32
#define CH2 129
#define BK 64

typedef __attribute__((ext_vector_type(8))) short bf16x8;
typedef __attribute__((ext_vector_type(4))) float f32x4;

#define AS1(p) ((__attribute__((address_space(1))) const void*)(p))
#define AS3(p) ((__attribute__((address_space(3))) void*)(p))

__device__ __forceinline__ float bf2f(unsigned short u) {
  union { unsigned u; float f; } c; c.u = ((unsigned)u) << 16; return c.f;
}

// ---------------- K0: fused [proj_w f32->bf16] + [emb gather + conv, 4 rows/block] ----------------
__global__ __launch_bounds__(256) void k_pre(const float* __restrict__ pw,
    __hip_bfloat16* __restrict__ Wbf,
    const int* __restrict__ x, const float* __restrict__ emb,
    const float* __restrict__ conv_w, const float* __restrict__ conv_b,
    unsigned* __restrict__ y) {
  const int bx = blockIdx.x;
  const int t = threadIdx.x;
  if (bx < 1024) {                       // cvt: 1024*256 == 512*512
    const int i = bx * 256 + t;
    Wbf[i] = __float2bfloat16(pw[i]);
    return;
  }
  const int blk = bx - 1024;             // 0..4095
  const int b = blk >> 10, i0 = (blk & 1023) * 4;
  const int d = t * 2;
  const float4 c0 = ((const float4*)conv_w)[d];
  const float4 c1 = ((const float4*)conv_w)[d + 1];
  const float ca[4] = {c0.x, c0.y, c0.z, c0.w};
  const float cb[4] = {c1.x, c1.y, c1.z, c1.w};
  const float2 bias2 = ((const float2*)conv_b)[t];

  float2 e[7];
#pragma unroll
  for (int q = 0; q < 7; ++q) e[q] = make_float2(0.f, 0.f);
#pragma unroll
  for (int q = 0; q < 7; ++q) {
    if (i0 + q < N_) {
      const int tok = x[b * N_ + i0 + q];
      e[q] = *(const float2*)(emb + (size_t)tok * D_ + d);
    }
  }
#pragma unroll
  for (int r = 0; r < 4; ++r) {
    float2 acc = bias2;
#pragma unroll
    for (int k = 0; k < 4; ++k) {
      acc.x += e[r + k].x * ca[k];
      acc.y += e[r + k].y * cb[k];
    }
    union { __hip_bfloat16 h[2]; unsigned u; } pk;
    pk.h[0] = __float2bfloat16(acc.x);
    pk.h[1] = __float2bfloat16(acc.y);
    y[(size_t)(b * N_ + i0 + r) * 256 + t] = pk.u;
  }
}

// ---------------- K1: h = y @ proj_w^T + proj_b (bf16 out) + t-partials ----------------
// BK=64, double-buffered LDS w/ prefetch, XOR-swizzled granules (conflict-free ds_read_b128)
__global__ __launch_bounds__(256) void k_gemm(const __hip_bfloat16* __restrict__ A,
    const __hip_bfloat16* __restrict__ W, const float* __restrict__ bias,
    const float* __restrict__ sw,
    __hip_bfloat16* __restrict__ C, float* __restrict__ tbP) {
  __shared__ __align__(16) __hip_bfloat16 As[2][128 * BK];
  __shared__ __align__(16) __hip_bfloat16 Bs[2][128 * BK];
  const int t = threadIdx.x;
  const int m0 = blockIdx.x * 128, n0 = blockIdx.y * 128;
  const int w = t >> 6, l = t & 63;
  const int quad = l >> 4, r16 = l & 15;
  const int wr = (w >> 1) * 64, wc = (w & 1) * 64;

  f32x4 acc[4][4];
#pragma unroll
  for (int a = 0; a < 4; ++a)
#pragma unroll
    for (int bq = 0; bq < 4; ++bq) acc[a][bq] = (f32x4){0.f, 0.f, 0.f, 0.f};

  // staging geometry: wave w covers rows 32w..32w+31 in 4 DMA instrs (8 rows each).
  // lane l: sub-row lr = l>>3, source granule = (l&7)^lr  (XOR swizzle; dest is
  // wave-uniform base + lane*16 so the swizzle is expressed on the SOURCE side)
  const int lr = l >> 3;
  const int lc = ((l & 7) ^ lr) * 8;        // element col within BK chunk
  const int arow = m0 + 32 * w + lr;
  const int brow = n0 + 32 * w + lr;
  const int ldsb = 4096 * w;                // byte base of this wave's chunk

#define STAGE(buf, kb)                                                            \
  _Pragma("unroll")                                                               \
  for (int ii = 0; ii < 4; ++ii) {                                                \
    __builtin_amdgcn_global_load_lds(                                             \
        AS1(A + (size_t)(arow + 8 * ii) * 512 + (kb) + lc),                       \
        AS3((char*)&As[buf][0] + ldsb + 1024 * ii), 16, 0, 0);                    \
    __builtin_amdgcn_global_load_lds(                                             \
        AS1(W + (size_t)(brow + 8 * ii) * 512 + (kb) + lc),                       \
        AS3((char*)&Bs[buf][0] + ldsb + 1024 * ii), 16, 0, 0);                    \
  }

  STAGE(0, 0)
  __syncthreads();

#pragma unroll 1
  for (int kt = 0; kt < 8; ++kt) {
    const int cur = kt & 1;
    if (kt < 7) { STAGE(1 - cur, (kt + 1) * BK) }   // prefetch; drained at loop-end barrier
#pragma unroll
    for (int kk = 0; kk < 2; ++kk) {
      // logical k-cols kk*32+quad*8 .. +7, granule-swizzled by row&7 (= r16&7)
      const int col_e = (kk * 32 + quad * 8) ^ ((r16 & 7) * 8);
      bf16x8 af[4], bfr[4];
#pragma unroll
      for (int ti = 0; ti < 4; ++ti)
        af[ti] = *(const bf16x8*)(&As[cur][(wr + ti * 16 + r16) * BK + col_e]);
#pragma unroll
      for (int tj = 0; tj < 4; ++tj)
        bfr[tj] = *(const bf16x8*)(&Bs[cur][(wc + tj * 16 + r16) * BK + col_e]);
#pragma unroll
      for (int ti = 0; ti < 4; ++ti)
#pragma unroll
        for (int tj = 0; tj < 4; ++tj)
          acc[ti][tj] = __builtin_amdgcn_mfma_f32_16x16x32_bf16(af[ti], bfr[tj], acc[ti][tj], 0, 0, 0);
    }
    __syncthreads();
  }
#undef STAGE

  float swv[4];
#pragma unroll
  for (int tj = 0; tj < 4; ++tj) swv[tj] = sw[n0 + wc + tj * 16 + r16];

  float tpart[4][4];
#pragma unroll
  for (int ti = 0; ti < 4; ++ti) {
    const int gi0 = m0 + wr + ti * 16 + quad * 4;
#pragma unroll
    for (int r = 0; r < 4; ++r) tpart[ti][r] = 0.f;
#pragma unroll
    for (int tj = 0; tj < 4; ++tj) {
      const int go = n0 + wc + tj * 16 + r16;
      const float bv = bias[go];
#pragma unroll
      for (int r = 0; r < 4; ++r) {
        const float cf = acc[ti][tj][r] + bv;
        C[(size_t)(gi0 + r) * 512 + go] = __float2bfloat16(cf);
        tpart[ti][r] = fmaf(cf, swv[tj], tpart[ti][r]);
      }
    }
  }
#pragma unroll
  for (int ti = 0; ti < 4; ++ti)
#pragma unroll
    for (int r = 0; r < 4; ++r) {
      float v = tpart[ti][r];
      v += __shfl_xor(v, 1); v += __shfl_xor(v, 2);
      v += __shfl_xor(v, 4); v += __shfl_xor(v, 8);
      tpart[ti][r] = v;
    }
  if (r16 == 0) {
    const int p = blockIdx.y * 2 + (w & 1);
#pragma unroll
    for (int ti = 0; ti < 4; ++ti)
#pragma unroll
      for (int r = 0; r < 4; ++r)
        tbP[(size_t)p * 16384 + (m0 + wr + ti * 16 + quad * 4 + r)] = tpart[ti][r];
  }
}

// helper: 4-way softmax from a t-window in LDS
__device__ __forceinline__ float4 softmax4(const float* __restrict__ tw, int base,
                                           int i, float bb) {
  const float s0 = tw[i - base] + bb;
  const int j2 = i & ~1;
  const float s1 = (tw[j2 - base] + tw[j2 + 1 - base]) * 0.5f + bb;
  const int j3 = (i / 3) * 3;
  const float s2 = (tw[j3 - base] + tw[j3 + 1 - base] + tw[j3 + 2 - base]) * (1.f / 3.f) + bb;
  const int j4 = i & ~3;
  const float s3 = (tw[j4 - base] + tw[j4 + 1 - base] + tw[j4 + 2 - base] + tw[j4 + 3 - base]) * 0.25f + bb;
  const float m = fmaxf(fmaxf(s0, s1), fmaxf(s2, s3));
  const float e0 = __expf(s0 - m), e1 = __expf(s1 - m), e2 = __expf(s2 - m), e3 = __expf(s3 - m);
  const float inv = 1.f / (e0 + e1 + e2 + e3);
  return make_float4(e0 * inv, e1 * inv, e2 * inv, e3 * inv);
}

// ---------------- K2: consensus attention; recomputes S rows from tbP in-block ----------------
__global__ __launch_bounds__(256) void k_attn(const float* __restrict__ tbP,
    const float* __restrict__ sb,
    float4* __restrict__ accnP, float* __restrict__ accdP) {
  __shared__ float twi[262];
  __shared__ float twj[135];
  __shared__ __align__(16) float4 Sch[CH2];
  const int bx = blockIdx.x;
  const int jc = bx & (JC2 - 1);
  const int rt = (bx >> 5) % RT;
  const int b  = bx / (JC2 * RT);
  const int t = threadIdx.x;
  const int j0 = jc * CH2;
  const int i0 = rt * 256;
  const int rowb = b * N_;
  for (int idx = t; idx < 262; idx += 256) {
    const int j = i0 - 3 + idx;
    float v = 0.f;
    if (j >= 0 && j < N_) {
#pragma unroll
      for (int p = 0; p < 8; ++p) v += tbP[(size_t)p * 16384 + rowb + j];
    }
    twi[idx] = v;
  }
  for (int idx = t; idx < 135; idx += 256) {
    const int j = j0 - 3 + idx;
    float v = 0.f;
    if (j >= 0 && j < N_) {
#pragma unroll
      for (int p = 0; p < 8; ++p) v += tbP[(size_t)p * 16384 + rowb + j];
    }
    twj[idx] = v;
  }
  __syncthreads();
  const float bb = sb[0];
  if (t < CH2 && j0 + t < L_) Sch[t] = softmax4(twj, j0 - 3, j0 + t, bb);
  const int i = i0 + t;
  const float4 si = softmax4(twi, i0 - 3, i, bb);   // safe for i>=L_ (unused)
  __syncthreads();
  if (i < L_) {
    const int len = min(CH2, L_ - j0);
    float l = 0.f, a0 = 0.f, a1 = 0.f, a2 = 0.f, a3 = 0.f;
#pragma unroll 4
    for (int jj = 0; jj < len; ++jj) {
      const float4 v = Sch[jj];
      const float dot = fmaf(si.x, v.x, fmaf(si.y, v.y, fmaf(si.z, v.z, si.w * v.w)));
      const float e = __expf(dot);   // dot in (0,1]; no max-shift needed
      l += e;
      a0 = fmaf(e, v.x, a0); a1 = fmaf(e, v.y, a1);
      a2 = fmaf(e, v.z, a2); a3 = fmaf(e, v.w, a3);
    }
    const size_t base = (size_t)jc * (B_ * L_) + b * L_ + i;
    accnP[base] = make_float4(a0, a1, a2, a3);
    accdP[base] = l;
  }
}

// ---------------- K3: 12-row tiles: reduce attn partials -> wgt, pool h once, downsample ----------------
__global__ __launch_bounds__(256) void k_fuse(const __hip_bfloat16* __restrict__ h,
    const float4* __restrict__ accnP, const float* __restrict__ accdP,
    float* __restrict__ out) {
  __shared__ __align__(16) float4 wgtS[12];
  const int bx = blockIdx.x;
  const int b = bx / 342, j12 = bx % 342;
  const int t = threadIdx.x, d = t * 2;
  const int r0 = 12 * j12;

  if (t < 192) {
    const int r = t >> 4, q = t & 15;
    const size_t i1 = (size_t)q * (B_ * L_) + b * L_ + r0 + r;
    const size_t i2 = (size_t)(q + 16) * (B_ * L_) + b * L_ + r0 + r;
    float4 nv = accnP[i1];
    const float4 n2 = accnP[i2];
    nv.x += n2.x; nv.y += n2.y; nv.z += n2.z; nv.w += n2.w;
    float dv = accdP[i1] + accdP[i2];
#pragma unroll
    for (int m = 8; m >= 1; m >>= 1) {
      nv.x += __shfl_xor(nv.x, m); nv.y += __shfl_xor(nv.y, m);
      nv.z += __shfl_xor(nv.z, m); nv.w += __shfl_xor(nv.w, m);
      dv   += __shfl_xor(dv, m);
    }
    if (q == 0) {
      const float inv = 1.f / dv;
      wgtS[r] = make_float4(nv.x * inv, nv.y * inv, nv.z * inv, nv.w * inv);
    }
  }
  __syncthreads();

  const __hip_bfloat16* hb = h + (size_t)b * N_ * D_;
  float2 hv[12];
#pragma unroll
  for (int q = 0; q < 12; ++q) {
    const int row = r0 + q;
    if (row < N_) {
      const ushort2 u = *(const ushort2*)(hb + (size_t)row * D_ + d);
      hv[q] = make_float2(bf2f(u.x), bf2f(u.y));
    } else {
      hv[q] = make_float2(0.f, 0.f);
    }
  }

  float2 p2[6], p3[4], p4[3];
#pragma unroll
  for (int g = 0; g < 6; ++g) {
    p2[g].x = (hv[2 * g].x + hv[2 * g + 1].x) * 0.5f;
    p2[g].y = (hv[2 * g].y + hv[2 * g + 1].y) * 0.5f;
  }
#pragma unroll
  for (int g = 0; g < 4; ++g) {
    p3[g].x = (hv[3 * g].x + hv[3 * g + 1].x + hv[3 * g + 2].x) * (1.f / 3.f);
    p3[g].y = (hv[3 * g].y + hv[3 * g + 1].y + hv[3 * g + 2].y) * (1.f / 3.f);
  }
#pragma unroll
  for (int g = 0; g < 3; ++g) {
    p4[g].x = (hv[4 * g].x + hv[4 * g + 1].x + hv[4 * g + 2].x + hv[4 * g + 3].x) * 0.25f;
    p4[g].y = (hv[4 * g].y + hv[4 * g + 1].y + hv[4 * g + 2].y + hv[4 * g + 3].y) * 0.25f;
  }

#pragma unroll
  for (int o = 0; o < 3; ++o) {
    const int orow = j12 * 3 + o;
    if (orow < 1024) {
      float ox = 0.f, oy = 0.f;
#pragma unroll
      for (int rr = 0; rr < 4; ++rr) {
        const int r = 4 * o + rr;
        const float4 wv = wgtS[r];
        const float2 p1 = hv[r];
        const float2 q2 = p2[r >> 1];
        const float2 q3 = p3[r / 3];
        const float2 q4 = p4[o];
        ox += wv.x * p1.x + wv.y * q2.x + wv.z * q3.x + wv.w * q4.x;
        oy += wv.x * p1.y + wv.y * q2.y + wv.z * q3.y + wv.w * q4.y;
      }
      float2 ov; ov.x = ox * 0.25f; ov.y = oy * 0.25f;
      *(float2*)(out + (size_t)(b * 1024 + orow) * D_ + d) = ov;
    }
  }
}

extern "C" void kernel_launch(void* const* d_in, const int* in_sizes, int n_in,
                              void* d_out, int out_size, void* d_ws, size_t ws_size,
                              hipStream_t stream) {
  const int*   x       = (const int*)d_in[0];
  const float* emb     = (const float*)d_in[1];
  const float* conv_w  = (const float*)d_in[2];
  const float* conv_b  = (const float*)d_in[3];
  const float* proj_w  = (const float*)d_in[4];
  const float* proj_b  = (const float*)d_in[5];
  const float* score_w = (const float*)d_in[6];
  const float* score_b = (const float*)d_in[7];
  float* out = (float*)d_out;

  char* ws = (char*)d_ws;
  size_t off = 0;
  __hip_bfloat16* Wbf = (__hip_bfloat16*)(ws + off); off += (size_t)512 * 512 * 2;
  char*           ybase = ws + off;                  off += (size_t)16384 * 512 * 2;
  __hip_bfloat16* h   = (__hip_bfloat16*)(ws + off); off += (size_t)16384 * 512 * 2;
  float*          tbP = (float*)(ws + off);          off += (size_t)8 * 16384 * 4;
  // partials alias the y buffer (y dead after k_gemm): 8.4 MB + 2.1 MB <= 16 MB
  unsigned* y     = (unsigned*)ybase;
  float4*   accnP = (float4*)ybase;
  float*    accdP = (float*)(ybase + (size_t)JC2 * B_ * L_ * 16);
  (void)in_sizes; (void)n_in; (void)out_size; (void)ws_size;

  k_pre<<<1024 + B_ * N_ / 4, 256, 0, stream>>>(proj_w, Wbf, x, emb, conv_w, conv_b, y);
  k_gemm<<<dim3(128, 4), 256, 0, stream>>>((const __hip_bfloat16*)y, Wbf, proj_b, score_w,
                                           h, tbP);
  k_attn<<<B_ * RT * JC2, 256, 0, stream>>>(tbP, score_b, accnP, accdP);
  k_fuse<<<B_ * 342, 256, 0, stream>>>(h, accnP, accdP, out);
}